// Round 12
// baseline (1026.317 us; speedup 1.0000x reference)
//
#include <hip/hip_runtime.h>
#include <hip/hip_bf16.h>
#include <stdint.h>

#define NE 8
#define HID 1024
#define FFN 4096
#define TOK 8192
#define TPE (TOK / NE)   // 1024 tokens per expert

typedef __attribute__((ext_vector_type(8))) short    bf16x8;
typedef __attribute__((ext_vector_type(4))) float    f32x4;
typedef __attribute__((ext_vector_type(4))) unsigned short ushort4v;
typedef __attribute__((ext_vector_type(8))) unsigned short ushort8v;

// ---------- helpers ----------

__device__ __forceinline__ unsigned short f2bf(float f) {
    union { float f; unsigned u; } c; c.f = f;
    unsigned r = c.u + 0x7fffu + ((c.u >> 16) & 1u);   // RNE, inputs finite
    return (unsigned short)(r >> 16);
}

__device__ __forceinline__ float gelu_tanh(float x) {
    const float c0 = 0.7978845608028654f;  // sqrt(2/pi)
    const float c1 = 0.044715f;
    float u = c0 * (x + c1 * x * x * x);
    float t = 1.0f - 2.0f / (1.0f + __expf(2.0f * u));
    return 0.5f * x * (1.0f + t);
}

typedef const __attribute__((address_space(1))) void gbl_void_t;
typedef __attribute__((address_space(3))) void lds_void_t;

__device__ __forceinline__ void gload_lds16(const void* g, void* l) {
    __builtin_amdgcn_global_load_lds((gbl_void_t*)g, (lds_void_t*)l, 16, 0, 0);
}

// ---------- merged prep: cvt x, cvt w1, transpose-cvt w2 (one launch) ------

#define XBLKS  ((TOK * HID) / 2048)              // 4096
#define W1BLKS ((NE * FFN * HID) / 2048)         // 16384
#define TBLKS  (NE * (FFN / 64) * (HID / 64))    // 8192

__global__ void prep_all(const float* __restrict__ x,  unsigned short* __restrict__ xb,
                         const float* __restrict__ w1, unsigned short* __restrict__ w1b,
                         const float* __restrict__ w2, unsigned short* __restrict__ w2t) {
    __shared__ unsigned short tile[64][65];
    int bid = blockIdx.x;
    if (bid < XBLKS + W1BLKS) {
        const float* in; unsigned short* out; size_t i;
        if (bid < XBLKS) { in = x;  out = xb;  i = ((size_t)bid * 256 + threadIdx.x) * 8; }
        else             { in = w1; out = w1b; i = ((size_t)(bid - XBLKS) * 256 + threadIdx.x) * 8; }
        f32x4 a = *(const f32x4*)(in + i);
        f32x4 b = *(const f32x4*)(in + i + 4);
        ushort8v o;
#pragma unroll
        for (int j = 0; j < 4; j++) { o[j] = f2bf(a[j]); o[4 + j] = f2bf(b[j]); }
        *(ushort8v*)(out + i) = o;
        return;
    }
    bid -= XBLKS + W1BLKS;
    const int e  = bid / ((FFN / 64) * (HID / 64));
    const int r_ = bid % ((FFN / 64) * (HID / 64));
    const int f0 = (r_ / (HID / 64)) * 64;
    const int h0 = (r_ % (HID / 64)) * 64;
    const float*     src = w2  + (size_t)e * FFN * HID;
    unsigned short*  dst = w2t + (size_t)e * HID * FFN;
    const int t  = threadIdx.x;
    const int tr = t >> 4;        // 0..15
    const int tc = (t & 15) * 4;  // 0..60
#pragma unroll
    for (int i = 0; i < 4; i++) {
        int f = i * 16 + tr;
        f32x4 v = *(const f32x4*)(src + (size_t)(f0 + f) * HID + h0 + tc);
#pragma unroll
        for (int j = 0; j < 4; j++) tile[f][tc + j] = f2bf(v[j]);
    }
    __syncthreads();
#pragma unroll
    for (int i = 0; i < 4; i++) {
        int h = i * 16 + tr;
        ushort4v o;
#pragma unroll
        for (int j = 0; j < 4; j++) o[j] = tile[tc + j][h];
        *(ushort4v*)(dst + (size_t)(h0 + h) * FFN + f0 + tc) = o;
    }
}

// ---------- GEMM-BT "hi-occupancy": BK=32, 64KB dbuf, 2 blocks/CU ----------
// C[M][N] = A[M][K]*B[N][K]^T per expert. BM=BN=256, BK=32, 8 waves (2Mx4N),
// 512 threads. LDS-BW roofline analysis: the 8-phase 1-block/CU kernels are
// LDS-bound (~320KB LDS traffic per K-tile vs ~620cyc MFMA); a single
// barrier-locked block leaves LDS idle during convergence. Fix: 2 co-resident
// blocks/CU interleave their (unsynchronized) LDS bursts.
// LDS layout: rows are 64B (BK=32); pack 2 rows per 128B line with XOR
// swizzle key ((row>>1)&7)<<4 on the 7-bit in-line offset — 64 lanes map to
// 64 distinct 16B slots (conflict-free), staging stays gload_lds-linear with
// pre-swizzled source (rule #21 both-sides-or-neither, consistency derived).
// Per tile: ph1 {12 ds_reads; bar; lgkm0; 16 MFMA (n0,n1); bar} ph2 {stage
// A,B(T+2) into just-freed regions; 16 MFMA (n2,n3); vmcnt(4); bar}.

template <int GX, int GY, bool GELU>
__global__ __launch_bounds__(512, 4)
void gemm_hi(const unsigned short* __restrict__ A,
             const unsigned short* __restrict__ B,
             void* __restrict__ Cout, int M, int N, int K) {
    constexpr int ABYTES = 256 * 32 * 2;   // 16384
    constexpr int BBYTES = 256 * 32 * 2;   // 16384
    constexpr int BUF = ABYTES + BBYTES;   // 32768
    constexpr int NWG = NE * GX * GY;

    __shared__ __align__(16) char lds[2 * BUF];   // 64 KB

    // ---- XCD-aware bijective swizzle (T1) ----
    const int lin = blockIdx.x;
    const int wid = (lin & 7) * (NWG >> 3) + (lin >> 3);
    const int e   = wid / (GX * GY);
    const int rem = wid % (GX * GY);
    const int m0  = (rem % GX) * 256;
    const int n0  = (rem / GX) * 256;

    const size_t K2 = (size_t)K * 2;
    const char* Ae = (const char*)(A + (size_t)e * M * K);
    const char* Be = (const char*)(B + (size_t)e * N * K);

    const int tid  = threadIdx.x;
    const int lane = tid & 63;
    const int w    = tid >> 6;
    const int wr   = w >> 2, wc = w & 3;
    const int fr   = lane & 15, fq = lane >> 4;

    // ---- staging: chunk c -> LDS byte c*16 (linear); source pre-swizzled.
    // unswizzle: line=c>>3, off=((c&7)<<4)^((line&7)<<4); row=(line<<1)|(off>>6); kb=off&63
    const int c0_  = tid, c1_ = tid + 512;
    const int ln0  = c0_ >> 3,  ln1 = c1_ >> 3;
    const int of0  = ((c0_ & 7) << 4) ^ ((ln0 & 7) << 4);
    const int of1  = ((c1_ & 7) << 4) ^ ((ln1 & 7) << 4);
    const int row0 = (ln0 << 1) | (of0 >> 6), kb0 = of0 & 63;
    const int row1 = (ln1 << 1) | (of1 >> 6), kb1 = of1 & 63;

    const char* aS0 = Ae + (size_t)(m0 + row0) * K2 + kb0;
    const char* aS1 = Ae + (size_t)(m0 + row1) * K2 + kb1;
    const char* bS0 = Be + (size_t)(n0 + row0) * K2 + kb0;
    const char* bS1 = Be + (size_t)(n0 + row1) * K2 + kb1;
    char* adst0 = lds + c0_ * 16;            char* adst1 = lds + c1_ * 16;
    char* bdst0 = lds + ABYTES + c0_ * 16;   char* bdst1 = lds + ABYTES + c1_ * 16;

    auto SA = [&](int kt, int p) {            // stage A tile kt -> buf p
        const size_t ko = (size_t)kt * 64;
        gload_lds16(aS0 + ko, adst0 + p * BUF);
        gload_lds16(aS1 + ko, adst1 + p * BUF);
    };
    auto SB = [&](int kt, int p) {            // stage B tile kt -> buf p
        const size_t ko = (size_t)kt * 64;
        gload_lds16(bS0 + ko, bdst0 + p * BUF);
        gload_lds16(bS1 + ko, bdst1 + p * BUF);
    };

    // ---- fragment read bases (swizzled) ----
    // A frag mi: byte = wr*8192 + mi*1024 + (fr>>1)*128 + axoff
    const int axoff = (((fr & 1) << 6) | (fq << 4)) ^ (((fr >> 1) & 7) << 4);
    const char* pa0 = lds + wr * 8192 + (fr >> 1) * 128 + axoff;
    const char* pb0 = lds + ABYTES + wc * 4096 + (fr >> 1) * 128 + axoff;
    const char* pa1 = pa0 + BUF;
    const char* pb1 = pb0 + BUF;

    f32x4 acc[8][4];
#pragma unroll
    for (int i = 0; i < 8; i++)
#pragma unroll
        for (int j = 0; j < 4; j++) acc[i][j] = f32x4{0.f, 0.f, 0.f, 0.f};

    bf16x8 a[8], b[4];
    auto RD = [&](const char* pa, const char* pb) {
#pragma unroll
        for (int mi = 0; mi < 8; mi++) a[mi] = *(const bf16x8*)(pa + mi * 1024);
#pragma unroll
        for (int ni = 0; ni < 4; ni++) b[ni] = *(const bf16x8*)(pb + ni * 1024);
    };
    auto MMH = [&](int nh) {                  // 16 MFMA: all mi x {nh*2, nh*2+1}
        __builtin_amdgcn_s_setprio(1);
#pragma unroll
        for (int mi = 0; mi < 8; mi++)
#pragma unroll
            for (int nj = 0; nj < 2; nj++) {
                const int ni = nh * 2 + nj;
                acc[mi][ni] = __builtin_amdgcn_mfma_f32_16x16x32_bf16(
                    a[mi], b[ni], acc[mi][ni], 0, 0, 0);
            }
        __builtin_amdgcn_s_setprio(0);
    };

#define BARRIER() __builtin_amdgcn_s_barrier()
#define LGKM0()   asm volatile("s_waitcnt lgkmcnt(0)" ::: "memory")
#define LGHINT()  asm volatile("s_waitcnt lgkmcnt(8)" ::: "memory")
#define VMW4()    asm volatile("s_waitcnt vmcnt(4)" ::: "memory")

    const int NT   = K / 32;
    const int NTm1 = NT - 1;

    // prologue: stage T0, T1; drain T0 (keep T1's 4 in flight)
    SA(0, 0); SB(0, 0); SA(1, 1); SB(1, 1);
    VMW4();
    BARRIER();

    const int NW = NT / 2;
    for (int ww = 0; ww < NW; ++ww) {
        const int T = 2 * ww;
        const int kt2 = (T + 2 < NT) ? T + 2 : NTm1;
        const int kt3 = (T + 3 < NT) ? T + 3 : NTm1;

        // ---- tile T (buf0) ----
        RD(pa0, pb0); LGHINT();
        BARRIER(); LGKM0();
        MMH(0);
        BARRIER();                            // regions of buf0 dead chip-wide
        SA(kt2, 0); SB(kt2, 0);
        MMH(1);
        VMW4();                               // T+1 published (counted, never 0)
        BARRIER();
        // ---- tile T+1 (buf1) ----
        RD(pa1, pb1); LGHINT();
        BARRIER(); LGKM0();
        MMH(0);
        BARRIER();
        SA(kt3, 1); SB(kt3, 1);
        MMH(1);
        VMW4();
        BARRIER();
    }
    asm volatile("s_waitcnt vmcnt(0)" ::: "memory");   // drain tail junk stages

    // epilogue: C/D layout col = lane&15, row = (lane>>4)*4 + r
    const int r0 = m0 + wr * 128 + fq * 4;
    const int c0 = n0 + wc * 64 + fr;
    if constexpr (GELU) {
        unsigned short* C = (unsigned short*)Cout + (size_t)e * M * N;
#pragma unroll
        for (int mi = 0; mi < 8; mi++)
#pragma unroll
            for (int ni = 0; ni < 4; ni++) {
                int row = r0 + mi * 16, col = c0 + ni * 16;
#pragma unroll
                for (int r = 0; r < 4; r++)
                    C[(size_t)(row + r) * N + col] = f2bf(gelu_tanh(acc[mi][ni][r]));
            }
    } else {
        float* C = (float*)Cout + (size_t)e * M * N;
#pragma unroll
        for (int mi = 0; mi < 8; mi++)
#pragma unroll
            for (int ni = 0; ni < 4; ni++) {
                int row = r0 + mi * 16, col = c0 + ni * 16;
#pragma unroll
                for (int r = 0; r < 4; r++)
                    C[(size_t)(row + r) * N + col] = acc[mi][ni][r];
            }
    }
#undef BARRIER
#undef LGKM0
#undef LGHINT
#undef VMW4
}

// ---------- 8-phase GEMM-BT (R11, proven) for GEMM2 ------------------------

template <int BN, int GX, int GY, bool GELU>
__global__ __launch_bounds__(512, 2)
void gemm8p(const unsigned short* __restrict__ A,
            const unsigned short* __restrict__ B,
            void* __restrict__ Cout, int M, int N, int K) {
    constexpr int BM = 256, BK = 64;
    constexpr int NH = BN / 128;
    constexpr int NI = 2 * NH;
    constexpr int LB = BN / 128;
    constexpr int S  = BN / 8;
    constexpr int ABYTES = BM * BK * 2;
    constexpr int BBYTES = BN * BK * 2;
    constexpr int BUF = ABYTES + BBYTES;
    constexpr int VMC = 2 + 2 * LB;
    constexpr int NWG = NE * GX * GY;

    __shared__ __align__(16) char lds[2 * BUF];

    const int lin = blockIdx.x;
    const int wid = (lin & 7) * (NWG >> 3) + (lin >> 3);
    const int e   = wid / (GX * GY);
    const int rem = wid % (GX * GY);
    const int m0  = (rem % GX) * BM;
    const int n0  = (rem / GX) * BN;

    const size_t K2 = (size_t)K * 2;
    const char* Ae = (const char*)(A + (size_t)e * M * K);
    const char* Be = (const char*)(B + (size_t)e * N * K);

    const int tid  = threadIdx.x;
    const int lane = tid & 63;
    const int w    = tid >> 6;
    const int wr   = w >> 2, wc = w & 3;
    const int fr   = lane & 15, fq = lane >> 4;

    const int rA  = tid >> 3;
    const int kb  = (tid & 7) * 16;
    const int kbs = kb ^ ((rA & 7) << 4);
    const char* aptr = Ae + (size_t)(m0 + rA) * K2 + kbs;
    const int   fB   = (rA / S) * 2 * S + (rA % S);
    const char* bptr = Be + (size_t)(n0 + fB) * K2 + kbs;
    char* dA0 = lds + rA * 128 + kb;
    char* dA1 = dA0 + BUF;
    char* dB0 = lds + ABYTES + fB * 128 + kb;
    char* dB1 = dB0 + BUF;

    auto SA = [&](int au, int kt, char* d) {
        const char* s = aptr + (size_t)kt * 128;
#pragma unroll
        for (int i = 0; i < 2; i++)
            gload_lds16(s + (size_t)(au * 64 + i * 128) * K2,
                        d + (au * 64 + i * 128) * 128);
    };
    auto SB = [&](int bu, int kt, char* d) {
        const char* s = bptr + (size_t)kt * 128;
#pragma unroll
        for (int i = 0; i < LB; i++)
            gload_lds16(s + (size_t)(bu * S + i * 128) * K2,
                        d + (bu * S + i * 128) * 128);
    };

    const int kx0 = (fq * 16) ^ ((lane & 7) << 4);
    const char* paA = lds + (wr * 128 + fr) * 128;
    const char* paB = lds + ABYTES + (wc * (BN / 4) + fr) * 128;
    const char* pa0k0 = paA + kx0;        const char* pa0k1 = paA + (kx0 ^ 64);
    const char* pa1k0 = pa0k0 + BUF;      const char* pa1k1 = pa0k1 + BUF;
    const char* pb0k0 = paB + kx0;        const char* pb0k1 = paB + (kx0 ^ 64);
    const char* pb1k0 = pb0k0 + BUF;      const char* pb1k1 = pb0k1 + BUF;

    f32x4 acc[8][NI];
#pragma unroll
    for (int i = 0; i < 8; i++)
#pragma unroll
        for (int j = 0; j < NI; j++) acc[i][j] = f32x4{0.f, 0.f, 0.f, 0.f};

    bf16x8 a[4][2], b0[NH][2], b1[NH][2];

    auto LDA = [&](const char* p0, const char* p1, int mq) {
#pragma unroll
        for (int mi = 0; mi < 4; mi++) {
            a[mi][0] = *(const bf16x8*)(p0 + mq * 8192 + mi * 2048);
            a[mi][1] = *(const bf16x8*)(p1 + mq * 8192 + mi * 2048);
        }
    };
    auto LDB = [&](const char* p0, const char* p1, int nq, bf16x8 (&bb)[NH][2]) {
#pragma unroll
        for (int ni = 0; ni < NH; ni++) {
            bb[ni][0] = *(const bf16x8*)(p0 + (nq * (BN / 8) + ni * 16) * 128);
            bb[ni][1] = *(const bf16x8*)(p1 + (nq * (BN / 8) + ni * 16) * 128);
        }
    };
    auto MMQ = [&](int mq, int nq, bf16x8 (&bb)[NH][2]) {
        __builtin_amdgcn_s_setprio(1);
#pragma unroll
        for (int mi = 0; mi < 4; mi++)
#pragma unroll
            for (int ni = 0; ni < NH; ni++) {
                f32x4& c = acc[mq * 4 + mi][nq * NH + ni];
                c = __builtin_amdgcn_mfma_f32_16x16x32_bf16(a[mi][0], bb[ni][0], c, 0, 0, 0);
                c = __builtin_amdgcn_mfma_f32_16x16x32_bf16(a[mi][1], bb[ni][1], c, 0, 0, 0);
            }
        __builtin_amdgcn_s_setprio(0);
    };

#define MIDBAR()  __builtin_amdgcn_s_barrier();                                      \
                  asm volatile("s_waitcnt lgkmcnt(0)" ::: "memory")
#define ENDBAR()  __builtin_amdgcn_s_barrier()
#define LGHINT()  asm volatile("s_waitcnt lgkmcnt(8)" ::: "memory")
#define VMW()     asm volatile("s_waitcnt vmcnt(%0)" :: "n"(VMC) : "memory")

    const int NT   = K / BK;
    const int NTm1 = NT - 1;

    SA(0, 0, dA0); SB(0, 0, dB0); SB(1, 0, dB0); SA(1, 0, dA0);
    SA(0, 1, dA1); SB(0, 1, dB1); SB(1, 1, dB1);
    VMW();
    __builtin_amdgcn_s_barrier();

    const int NW = NT / 2;
    for (int ww = 0; ww < NW; ++ww) {
        const int T = 2 * ww;
        const int kt1 = T + 1;
        const int kt2 = (T + 2 < NT) ? T + 2 : NTm1;
        const int kt3 = (T + 3 < NT) ? T + 3 : NTm1;

        LDA(pa0k0, pa0k1, 0); LDB(pb0k0, pb0k1, 0, b0); SA(1, kt1, dA1); LGHINT();
        MIDBAR(); MMQ(0, 0, b0); ENDBAR();
        LDB(pb0k0, pb0k1, 1, b1); SA(0, kt2, dA0);
        MIDBAR(); MMQ(0, 1, b1); ENDBAR();
        LDA(pa0k0, pa0k1, 1); SB(0, kt2, dB0);
        MIDBAR(); MMQ(1, 1, b1); ENDBAR();
        SB(1, kt2, dB0);
        MIDBAR(); MMQ(1, 0, b0); VMW(); ENDBAR();
        LDA(pa1k0, pa1k1, 0); LDB(pb1k0, pb1k1, 0, b0); SA(1, kt2, dA0); LGHINT();
        MIDBAR(); MMQ(0, 0, b0); ENDBAR();
        LDB(pb1k0, pb1k1, 1, b1); SA(0, kt3, dA1);
        MIDBAR(); MMQ(0, 1, b1); ENDBAR();
        LDA(pa1k0, pa1k1, 1); SB(0, kt3, dB1);
        MIDBAR(); MMQ(1, 1, b1); ENDBAR();
        SB(1, kt3, dB1);
        MIDBAR(); MMQ(1, 0, b0); VMW(); ENDBAR();
    }
    asm volatile("s_waitcnt vmcnt(0)" ::: "memory");

    const int r0 = m0 + wr * 128 + fq * 4;
    const int c0 = n0 + wc * (BN / 4) + fr;
    if constexpr (GELU) {
        unsigned short* C = (unsigned short*)Cout + (size_t)e * M * N;
#pragma unroll
        for (int mi = 0; mi < 8; mi++)
#pragma unroll
            for (int ni = 0; ni < NI; ni++) {
                int row = r0 + mi * 16, col = c0 + ni * 16;
#pragma unroll
                for (int r = 0; r < 4; r++)
                    C[(size_t)(row + r) * N + col] = f2bf(gelu_tanh(acc[mi][ni][r]));
            }
    } else {
        float* C = (float*)Cout + (size_t)e * M * N;
#pragma unroll
        for (int mi = 0; mi < 8; mi++)
#pragma unroll
            for (int ni = 0; ni < NI; ni++) {
                int row = r0 + mi * 16, col = c0 + ni * 16;
#pragma unroll
                for (int r = 0; r < 4; r++)
                    C[(size_t)(row + r) * N + col] = acc[mi][ni][r];
            }
    }
#undef MIDBAR
#undef ENDBAR
#undef LGHINT
#undef VMW
}

// ---------- fallback: fused fp32, zero workspace (correctness insurance) ----------

__global__ void fused_fallback(const float* __restrict__ x,
                               const float* __restrict__ w1,
                               const float* __restrict__ w2,
                               float* __restrict__ out) {
    __shared__ float xs[HID];
    __shared__ float hs[FFN];
    const int tok = blockIdx.x;
    const int e   = tok / TPE;
    const float* w1e = w1 + (size_t)e * FFN * HID;
    const float* w2e = w2 + (size_t)e * FFN * HID;
    const int t = threadIdx.x;
    for (int i = t; i < HID; i += 256) xs[i] = x[(size_t)tok * HID + i];
    __syncthreads();
    for (int f = t; f < FFN; f += 256) {
        const float* wr_ = w1e + (size_t)f * HID;
        float s = 0.f;
        for (int k = 0; k < HID; k++) s += xs[k] * wr_[k];
        hs[f] = gelu_tanh(s);
    }
    __syncthreads();
    for (int h = t; h < HID; h += 256) {
        float s = 0.f;
        for (int f = 0; f < FFN; f++) s += hs[f] * w2e[(size_t)f * HID + h];
        out[(size_t)tok * HID + h] = s;
    }
}

// ---------- launch ----------

extern "C" void kernel_launch(void* const* d_in, const int* in_sizes, int n_in,
                              void* d_out, int out_size, void* d_ws, size_t ws_size,
                              hipStream_t stream) {
    const float* x  = (const float*)d_in[0];
    const float* w1 = (const float*)d_in[1];
    const float* w2 = (const float*)d_in[2];
    float* out = (float*)d_out;

    const size_t XB  = (size_t)TOK * HID * 2;        // 16 MB  bf16 x
    const size_t W1B = (size_t)NE * FFN * HID * 2;   // 64 MB  bf16 w1
    const size_t W2B = W1B;                          // 64 MB  bf16 w2t
    const size_t HB  = (size_t)TOK * FFN * 2;        // 64 MB  bf16 h
    const size_t need = XB + W1B + W2B + HB;         // 208 MB

    if (ws_size >= need) {
        char* ws = (char*)d_ws;
        unsigned short* xb  = (unsigned short*)ws;
        unsigned short* w1b = (unsigned short*)(ws + XB);
        unsigned short* w2t = (unsigned short*)(ws + XB + W1B);
        unsigned short* hb  = (unsigned short*)(ws + XB + W1B + W2B);

        prep_all<<<XBLKS + W1BLKS + TBLKS, 256, 0, stream>>>(x, xb, w1, w1b, w2, w2t);

        // GEMM1: h = gelu(x @ w1^T)  -> 512 blocks, 2 blocks/CU co-resident
        gemm_hi<TPE / 256, FFN / 256, true><<<NE * (TPE / 256) * (FFN / 256), 512, 0, stream>>>(
            xb, w1b, hb, TPE, FFN, HID);
        // GEMM2: out = h @ w2t^T     -> 256 blocks (R11 proven 8-phase)
        gemm8p<128, TPE / 256, HID / 128, false><<<NE * (TPE / 256) * (HID / 128), 512, 0, stream>>>(
            hb, w2t, out, TPE, HID, FFN);
    } else {
        fused_fallback<<<TOK, 256, 0, stream>>>(x, w1, w2, out);
    }
}

// Round 13
// 246.475 us; speedup vs baseline: 4.1640x; 4.1640x over previous
//
#include <hip/hip_runtime.h>
#include <hip/hip_bf16.h>
#include <stdint.h>

#define NE 8
#define HID 1024
#define FFN 4096
#define TOK 8192
#define TPE (TOK / NE)   // 1024 tokens per expert

typedef __attribute__((ext_vector_type(8))) short    bf16x8;
typedef __attribute__((ext_vector_type(4))) float    f32x4;
typedef __attribute__((ext_vector_type(4))) unsigned short ushort4v;
typedef __attribute__((ext_vector_type(8))) unsigned short ushort8v;

// ---------- helpers ----------

__device__ __forceinline__ unsigned short f2bf(float f) {
    union { float f; unsigned u; } c; c.f = f;
    unsigned r = c.u + 0x7fffu + ((c.u >> 16) & 1u);   // RNE, inputs finite
    return (unsigned short)(r >> 16);
}

__device__ __forceinline__ float gelu_tanh(float x) {
    const float c0 = 0.7978845608028654f;  // sqrt(2/pi)
    const float c1 = 0.044715f;
    float u = c0 * (x + c1 * x * x * x);
    float t = 1.0f - 2.0f / (1.0f + __expf(2.0f * u));
    return 0.5f * x * (1.0f + t);
}

typedef const __attribute__((address_space(1))) void gbl_void_t;
typedef __attribute__((address_space(3))) void lds_void_t;

__device__ __forceinline__ void gload_lds16(const void* g, void* l) {
    __builtin_amdgcn_global_load_lds((gbl_void_t*)g, (lds_void_t*)l, 16, 0, 0);
}

// ---------- merged prep: cvt x, cvt w1, transpose-cvt w2 (one launch) ------

#define XBLKS  ((TOK * HID) / 2048)              // 4096
#define W1BLKS ((NE * FFN * HID) / 2048)         // 16384
#define TBLKS  (NE * (FFN / 64) * (HID / 64))    // 8192

__global__ void prep_all(const float* __restrict__ x,  unsigned short* __restrict__ xb,
                         const float* __restrict__ w1, unsigned short* __restrict__ w1b,
                         const float* __restrict__ w2, unsigned short* __restrict__ w2t) {
    __shared__ unsigned short tile[64][65];
    int bid = blockIdx.x;
    if (bid < XBLKS + W1BLKS) {
        const float* in; unsigned short* out; size_t i;
        if (bid < XBLKS) { in = x;  out = xb;  i = ((size_t)bid * 256 + threadIdx.x) * 8; }
        else             { in = w1; out = w1b; i = ((size_t)(bid - XBLKS) * 256 + threadIdx.x) * 8; }
        f32x4 a = *(const f32x4*)(in + i);
        f32x4 b = *(const f32x4*)(in + i + 4);
        ushort8v o;
#pragma unroll
        for (int j = 0; j < 4; j++) { o[j] = f2bf(a[j]); o[4 + j] = f2bf(b[j]); }
        *(ushort8v*)(out + i) = o;
        return;
    }
    bid -= XBLKS + W1BLKS;
    const int e  = bid / ((FFN / 64) * (HID / 64));
    const int r_ = bid % ((FFN / 64) * (HID / 64));
    const int f0 = (r_ / (HID / 64)) * 64;
    const int h0 = (r_ % (HID / 64)) * 64;
    const float*     src = w2  + (size_t)e * FFN * HID;
    unsigned short*  dst = w2t + (size_t)e * HID * FFN;
    const int t  = threadIdx.x;
    const int tr = t >> 4;        // 0..15
    const int tc = (t & 15) * 4;  // 0..60
#pragma unroll
    for (int i = 0; i < 4; i++) {
        int f = i * 16 + tr;
        f32x4 v = *(const f32x4*)(src + (size_t)(f0 + f) * HID + h0 + tc);
#pragma unroll
        for (int j = 0; j < 4; j++) tile[f][tc + j] = f2bf(v[j]);
    }
    __syncthreads();
#pragma unroll
    for (int i = 0; i < 4; i++) {
        int h = i * 16 + tr;
        ushort4v o;
#pragma unroll
        for (int j = 0; j < 4; j++) o[j] = tile[tc + j][h];
        *(ushort4v*)(dst + (size_t)(h0 + h) * FFN + f0 + tc) = o;
    }
}

// ---------- GEMM-BT "md": 128x128, BK=32, dbuf 32KB, 3 blocks/CU -----------
// C[M][N]=A[M][K]*B[N][K]^T per expert. 256 threads (4 waves, 2Mx2N), dbuf
// LDS 32KB, counted vmcnt(4), BK=32 swizzle packing (2 rows per 128B line,
// XOR key ((line&7)<<4) — correctness proven in R12 which passed absmax;
// R12's perf disaster was the launch_bounds(512,4)->64-VGPR spill, fixed
// here with (256,3) => 3 blocks/CU, VGPR cap ~170 (est ~135 used).
// Per tile: {8 ds_reads; BAR; lgkm0; 8 MFMA; BAR(all reads drained chip-
// wide); stage T+2 into freed buf; 8 MFMA; vmcnt(4)(T+1 published); BAR}.

template <int GX, int GY, bool GELU>
__global__ __launch_bounds__(256, 3)
void gemm_md(const unsigned short* __restrict__ A,
             const unsigned short* __restrict__ B,
             void* __restrict__ Cout, int M, int N, int K) {
    constexpr int ABYTES = 128 * 32 * 2;   // 8192
    constexpr int BUF = 2 * ABYTES;        // 16384 (A+B)
    constexpr int NWG = NE * GX * GY;

    __shared__ __align__(16) char lds[2 * BUF];   // 32 KB

    // ---- XCD-aware bijective swizzle (T1) ----
    const int lin = blockIdx.x;
    const int wid = (lin & 7) * (NWG >> 3) + (lin >> 3);
    const int e   = wid / (GX * GY);
    const int rem = wid % (GX * GY);
    const int m0  = (rem % GX) * 128;
    const int n0  = (rem / GX) * 128;

    const size_t K2 = (size_t)K * 2;
    const char* Ae = (const char*)(A + (size_t)e * M * K);
    const char* Be = (const char*)(B + (size_t)e * N * K);

    const int tid  = threadIdx.x;
    const int lane = tid & 63;
    const int w    = tid >> 6;
    const int wr   = w >> 1, wc = w & 1;
    const int fr   = lane & 15, fq = lane >> 4;

    // ---- staging: chunk c -> LDS byte c*16 linear; source pre-swizzled ----
    const char* aS[2]; const char* bS[2];
    char* adst[2]; char* bdst[2];
#pragma unroll
    for (int j = 0; j < 2; j++) {
        const int c    = tid + 256 * j;
        const int line = c >> 3;
        const int off  = ((c & 7) << 4) ^ ((line & 7) << 4);
        const int row  = (line << 1) | (off >> 6);
        const int kbo  = off & 63;
        aS[j] = Ae + (size_t)(m0 + row) * K2 + kbo;
        bS[j] = Be + (size_t)(n0 + row) * K2 + kbo;
        adst[j] = lds + c * 16;
        bdst[j] = lds + ABYTES + c * 16;
    }
    auto SA = [&](int kt, int p) {
        const size_t ko = (size_t)kt * 64;
        gload_lds16(aS[0] + ko, adst[0] + p * BUF);
        gload_lds16(aS[1] + ko, adst[1] + p * BUF);
    };
    auto SB = [&](int kt, int p) {
        const size_t ko = (size_t)kt * 64;
        gload_lds16(bS[0] + ko, bdst[0] + p * BUF);
        gload_lds16(bS[1] + ko, bdst[1] + p * BUF);
    };

    // ---- fragment read bases (swizzled; one b128 per frag per tile) ----
    const int axoff = (((fr & 1) << 6) | (fq << 4)) ^ (((fr >> 1) & 7) << 4);
    const char* pa0 = lds + wr * 4096 + (fr >> 1) * 128 + axoff;
    const char* pb0 = lds + ABYTES + wc * 4096 + (fr >> 1) * 128 + axoff;
    const char* pa1 = pa0 + BUF;
    const char* pb1 = pb0 + BUF;

    f32x4 acc[4][4];
#pragma unroll
    for (int i = 0; i < 4; i++)
#pragma unroll
        for (int j = 0; j < 4; j++) acc[i][j] = f32x4{0.f, 0.f, 0.f, 0.f};

    bf16x8 a[4], b[4];
    auto RD = [&](const char* pa, const char* pb) {
#pragma unroll
        for (int mi = 0; mi < 4; mi++) a[mi] = *(const bf16x8*)(pa + mi * 1024);
#pragma unroll
        for (int ni = 0; ni < 4; ni++) b[ni] = *(const bf16x8*)(pb + ni * 1024);
    };
    auto MMH = [&](int nh) {                  // 8 MFMA: mi x {nh*2, nh*2+1}
        __builtin_amdgcn_s_setprio(1);
#pragma unroll
        for (int mi = 0; mi < 4; mi++)
#pragma unroll
            for (int nj = 0; nj < 2; nj++) {
                const int ni = nh * 2 + nj;
                acc[mi][ni] = __builtin_amdgcn_mfma_f32_16x16x32_bf16(
                    a[mi], b[ni], acc[mi][ni], 0, 0, 0);
            }
        __builtin_amdgcn_s_setprio(0);
    };

#define BARRIER() __builtin_amdgcn_s_barrier()
#define LGKM0()   asm volatile("s_waitcnt lgkmcnt(0)" ::: "memory")
#define VMW4()    asm volatile("s_waitcnt vmcnt(4)" ::: "memory")

    const int NT   = K / 32;
    const int NTm1 = NT - 1;

    SA(0, 0); SB(0, 0); SA(1, 1); SB(1, 1);
    VMW4();
    BARRIER();

    const int NW = NT / 2;
    for (int ww = 0; ww < NW; ++ww) {
        const int T = 2 * ww;
        const int kt2 = (T + 2 < NT) ? T + 2 : NTm1;
        const int kt3 = (T + 3 < NT) ? T + 3 : NTm1;

        // ---- tile T (buf0) ----
        RD(pa0, pb0);
        BARRIER(); LGKM0();
        MMH(0);
        BARRIER();                  // all waves' reads of buf0 drained
        SA(kt2, 0); SB(kt2, 0);
        MMH(1);
        VMW4();                     // T+1 published (counted, never 0)
        BARRIER();
        // ---- tile T+1 (buf1) ----
        RD(pa1, pb1);
        BARRIER(); LGKM0();
        MMH(0);
        BARRIER();
        SA(kt3, 1); SB(kt3, 1);
        MMH(1);
        VMW4();
        BARRIER();
    }
    asm volatile("s_waitcnt vmcnt(0)" ::: "memory");   // drain tail junk stages

    // epilogue: C/D layout col = lane&15, row = (lane>>4)*4 + r
    const int r0 = m0 + wr * 64 + fq * 4;
    const int c0 = n0 + wc * 64 + fr;
    if constexpr (GELU) {
        unsigned short* C = (unsigned short*)Cout + (size_t)e * M * N;
#pragma unroll
        for (int mi = 0; mi < 4; mi++)
#pragma unroll
            for (int ni = 0; ni < 4; ni++) {
                int row = r0 + mi * 16, col = c0 + ni * 16;
#pragma unroll
                for (int r = 0; r < 4; r++)
                    C[(size_t)(row + r) * N + col] = f2bf(gelu_tanh(acc[mi][ni][r]));
            }
    } else {
        float* C = (float*)Cout + (size_t)e * M * N;
#pragma unroll
        for (int mi = 0; mi < 4; mi++)
#pragma unroll
            for (int ni = 0; ni < 4; ni++) {
                int row = r0 + mi * 16, col = c0 + ni * 16;
#pragma unroll
                for (int r = 0; r < 4; r++)
                    C[(size_t)(row + r) * N + col] = acc[mi][ni][r];
            }
    }
#undef BARRIER
#undef LGKM0
#undef VMW4
}

// ---------- 8-phase GEMM-BT (R11, proven) for GEMM2 ------------------------

template <int BN, int GX, int GY, bool GELU>
__global__ __launch_bounds__(512, 2)
void gemm8p(const unsigned short* __restrict__ A,
            const unsigned short* __restrict__ B,
            void* __restrict__ Cout, int M, int N, int K) {
    constexpr int BM = 256, BK = 64;
    constexpr int NH = BN / 128;
    constexpr int NI = 2 * NH;
    constexpr int LB = BN / 128;
    constexpr int S  = BN / 8;
    constexpr int ABYTES = BM * BK * 2;
    constexpr int BBYTES = BN * BK * 2;
    constexpr int BUF = ABYTES + BBYTES;
    constexpr int VMC = 2 + 2 * LB;
    constexpr int NWG = NE * GX * GY;

    __shared__ __align__(16) char lds[2 * BUF];

    const int lin = blockIdx.x;
    const int wid = (lin & 7) * (NWG >> 3) + (lin >> 3);
    const int e   = wid / (GX * GY);
    const int rem = wid % (GX * GY);
    const int m0  = (rem % GX) * BM;
    const int n0  = (rem / GX) * BN;

    const size_t K2 = (size_t)K * 2;
    const char* Ae = (const char*)(A + (size_t)e * M * K);
    const char* Be = (const char*)(B + (size_t)e * N * K);

    const int tid  = threadIdx.x;
    const int lane = tid & 63;
    const int w    = tid >> 6;
    const int wr   = w >> 2, wc = w & 3;
    const int fr   = lane & 15, fq = lane >> 4;

    const int rA  = tid >> 3;
    const int kb  = (tid & 7) * 16;
    const int kbs = kb ^ ((rA & 7) << 4);
    const char* aptr = Ae + (size_t)(m0 + rA) * K2 + kbs;
    const int   fB   = (rA / S) * 2 * S + (rA % S);
    const char* bptr = Be + (size_t)(n0 + fB) * K2 + kbs;
    char* dA0 = lds + rA * 128 + kb;
    char* dA1 = dA0 + BUF;
    char* dB0 = lds + ABYTES + fB * 128 + kb;
    char* dB1 = dB0 + BUF;

    auto SA = [&](int au, int kt, char* d) {
        const char* s = aptr + (size_t)kt * 128;
#pragma unroll
        for (int i = 0; i < 2; i++)
            gload_lds16(s + (size_t)(au * 64 + i * 128) * K2,
                        d + (au * 64 + i * 128) * 128);
    };
    auto SB = [&](int bu, int kt, char* d) {
        const char* s = bptr + (size_t)kt * 128;
#pragma unroll
        for (int i = 0; i < LB; i++)
            gload_lds16(s + (size_t)(bu * S + i * 128) * K2,
                        d + (bu * S + i * 128) * 128);
    };

    const int kx0 = (fq * 16) ^ ((lane & 7) << 4);
    const char* paA = lds + (wr * 128 + fr) * 128;
    const char* paB = lds + ABYTES + (wc * (BN / 4) + fr) * 128;
    const char* pa0k0 = paA + kx0;        const char* pa0k1 = paA + (kx0 ^ 64);
    const char* pa1k0 = pa0k0 + BUF;      const char* pa1k1 = pa0k1 + BUF;
    const char* pb0k0 = paB + kx0;        const char* pb0k1 = paB + (kx0 ^ 64);
    const char* pb1k0 = pb0k0 + BUF;      const char* pb1k1 = pb0k1 + BUF;

    f32x4 acc[8][NI];
#pragma unroll
    for (int i = 0; i < 8; i++)
#pragma unroll
        for (int j = 0; j < NI; j++) acc[i][j] = f32x4{0.f, 0.f, 0.f, 0.f};

    bf16x8 a[4][2], b0[NH][2], b1[NH][2];

    auto LDA = [&](const char* p0, const char* p1, int mq) {
#pragma unroll
        for (int mi = 0; mi < 4; mi++) {
            a[mi][0] = *(const bf16x8*)(p0 + mq * 8192 + mi * 2048);
            a[mi][1] = *(const bf16x8*)(p1 + mq * 8192 + mi * 2048);
        }
    };
    auto LDB = [&](const char* p0, const char* p1, int nq, bf16x8 (&bb)[NH][2]) {
#pragma unroll
        for (int ni = 0; ni < NH; ni++) {
            bb[ni][0] = *(const bf16x8*)(p0 + (nq * (BN / 8) + ni * 16) * 128);
            bb[ni][1] = *(const bf16x8*)(p1 + (nq * (BN / 8) + ni * 16) * 128);
        }
    };
    auto MMQ = [&](int mq, int nq, bf16x8 (&bb)[NH][2]) {
        __builtin_amdgcn_s_setprio(1);
#pragma unroll
        for (int mi = 0; mi < 4; mi++)
#pragma unroll
            for (int ni = 0; ni < NH; ni++) {
                f32x4& c = acc[mq * 4 + mi][nq * NH + ni];
                c = __builtin_amdgcn_mfma_f32_16x16x32_bf16(a[mi][0], bb[ni][0], c, 0, 0, 0);
                c = __builtin_amdgcn_mfma_f32_16x16x32_bf16(a[mi][1], bb[ni][1], c, 0, 0, 0);
            }
        __builtin_amdgcn_s_setprio(0);
    };

#define MIDBAR()  __builtin_amdgcn_s_barrier();                                      \
                  asm volatile("s_waitcnt lgkmcnt(0)" ::: "memory")
#define ENDBAR()  __builtin_amdgcn_s_barrier()
#define LGHINT()  asm volatile("s_waitcnt lgkmcnt(8)" ::: "memory")
#define VMW()     asm volatile("s_waitcnt vmcnt(%0)" :: "n"(VMC) : "memory")

    const int NT   = K / BK;
    const int NTm1 = NT - 1;

    SA(0, 0, dA0); SB(0, 0, dB0); SB(1, 0, dB0); SA(1, 0, dA0);
    SA(0, 1, dA1); SB(0, 1, dB1); SB(1, 1, dB1);
    VMW();
    __builtin_amdgcn_s_barrier();

    const int NW = NT / 2;
    for (int ww = 0; ww < NW; ++ww) {
        const int T = 2 * ww;
        const int kt1 = T + 1;
        const int kt2 = (T + 2 < NT) ? T + 2 : NTm1;
        const int kt3 = (T + 3 < NT) ? T + 3 : NTm1;

        LDA(pa0k0, pa0k1, 0); LDB(pb0k0, pb0k1, 0, b0); SA(1, kt1, dA1); LGHINT();
        MIDBAR(); MMQ(0, 0, b0); ENDBAR();
        LDB(pb0k0, pb0k1, 1, b1); SA(0, kt2, dA0);
        MIDBAR(); MMQ(0, 1, b1); ENDBAR();
        LDA(pa0k0, pa0k1, 1); SB(0, kt2, dB0);
        MIDBAR(); MMQ(1, 1, b1); ENDBAR();
        SB(1, kt2, dB0);
        MIDBAR(); MMQ(1, 0, b0); VMW(); ENDBAR();
        LDA(pa1k0, pa1k1, 0); LDB(pb1k0, pb1k1, 0, b0); SA(1, kt2, dA0); LGHINT();
        MIDBAR(); MMQ(0, 0, b0); ENDBAR();
        LDB(pb1k0, pb1k1, 1, b1); SA(0, kt3, dA1);
        MIDBAR(); MMQ(0, 1, b1); ENDBAR();
        LDA(pa1k0, pa1k1, 1); SB(0, kt3, dB1);
        MIDBAR(); MMQ(1, 1, b1); ENDBAR();
        SB(1, kt3, dB1);
        MIDBAR(); MMQ(1, 0, b0); VMW(); ENDBAR();
    }
    asm volatile("s_waitcnt vmcnt(0)" ::: "memory");

    const int r0 = m0 + wr * 128 + fq * 4;
    const int c0 = n0 + wc * (BN / 4) + fr;
    if constexpr (GELU) {
        unsigned short* C = (unsigned short*)Cout + (size_t)e * M * N;
#pragma unroll
        for (int mi = 0; mi < 8; mi++)
#pragma unroll
            for (int ni = 0; ni < NI; ni++) {
                int row = r0 + mi * 16, col = c0 + ni * 16;
#pragma unroll
                for (int r = 0; r < 4; r++)
                    C[(size_t)(row + r) * N + col] = f2bf(gelu_tanh(acc[mi][ni][r]));
            }
    } else {
        float* C = (float*)Cout + (size_t)e * M * N;
#pragma unroll
        for (int mi = 0; mi < 8; mi++)
#pragma unroll
            for (int ni = 0; ni < NI; ni++) {
                int row = r0 + mi * 16, col = c0 + ni * 16;
#pragma unroll
                for (int r = 0; r < 4; r++)
                    C[(size_t)(row + r) * N + col] = acc[mi][ni][r];
            }
    }
#undef MIDBAR
#undef ENDBAR
#undef LGHINT
#undef VMW
}

// ---------- fallback: fused fp32, zero workspace (correctness insurance) ----------

__global__ void fused_fallback(const float* __restrict__ x,
                               const float* __restrict__ w1,
                               const float* __restrict__ w2,
                               float* __restrict__ out) {
    __shared__ float xs[HID];
    __shared__ float hs[FFN];
    const int tok = blockIdx.x;
    const int e   = tok / TPE;
    const float* w1e = w1 + (size_t)e * FFN * HID;
    const float* w2e = w2 + (size_t)e * FFN * HID;
    const int t = threadIdx.x;
    for (int i = t; i < HID; i += 256) xs[i] = x[(size_t)tok * HID + i];
    __syncthreads();
    for (int f = t; f < FFN; f += 256) {
        const float* wr_ = w1e + (size_t)f * HID;
        float s = 0.f;
        for (int k = 0; k < HID; k++) s += xs[k] * wr_[k];
        hs[f] = gelu_tanh(s);
    }
    __syncthreads();
    for (int h = t; h < HID; h += 256) {
        float s = 0.f;
        for (int f = 0; f < FFN; f++) s += hs[f] * w2e[(size_t)f * HID + h];
        out[(size_t)tok * HID + h] = s;
    }
}

// ---------- launch ----------

extern "C" void kernel_launch(void* const* d_in, const int* in_sizes, int n_in,
                              void* d_out, int out_size, void* d_ws, size_t ws_size,
                              hipStream_t stream) {
    const float* x  = (const float*)d_in[0];
    const float* w1 = (const float*)d_in[1];
    const float* w2 = (const float*)d_in[2];
    float* out = (float*)d_out;

    const size_t XB  = (size_t)TOK * HID * 2;        // 16 MB  bf16 x
    const size_t W1B = (size_t)NE * FFN * HID * 2;   // 64 MB  bf16 w1
    const size_t W2B = W1B;                          // 64 MB  bf16 w2t
    const size_t HB  = (size_t)TOK * FFN * 2;        // 64 MB  bf16 h
    const size_t need = XB + W1B + W2B + HB;         // 208 MB

    if (ws_size >= need) {
        char* ws = (char*)d_ws;
        unsigned short* xb  = (unsigned short*)ws;
        unsigned short* w1b = (unsigned short*)(ws + XB);
        unsigned short* w2t = (unsigned short*)(ws + XB + W1B);
        unsigned short* hb  = (unsigned short*)(ws + XB + W1B + W2B);

        prep_all<<<XBLKS + W1BLKS + TBLKS, 256, 0, stream>>>(x, xb, w1, w1b, w2, w2t);

        // GEMM1: h = gelu(x @ w1^T) -> 2048 blocks of 256 thr, 3 blocks/CU
        gemm_md<TPE / 128, FFN / 128, true>
            <<<NE * (TPE / 128) * (FFN / 128), 256, 0, stream>>>(
                xb, w1b, hb, TPE, FFN, HID);
        // GEMM2: out = h @ w2t^T    -> 256 blocks (R11 proven 8-phase)
        gemm8p<128, TPE / 256, HID / 128, false><<<NE * (TPE / 256) * (HID / 128), 512, 0, stream>>>(
            hb, w2t, out, TPE, HID, FFN);
    } else {
        fused_fallback<<<TOK, 256, 0, stream>>>(x, w1, w2, out);
    }
}

// Round 14
// 231.815 us; speedup vs baseline: 4.4273x; 1.0632x over previous
//
#include <hip/hip_runtime.h>
#include <hip/hip_bf16.h>
#include <stdint.h>

#define NE 8
#define HID 1024
#define FFN 4096
#define TOK 8192
#define TPE (TOK / NE)   // 1024 tokens per expert

typedef __attribute__((ext_vector_type(8))) short    bf16x8;
typedef __attribute__((ext_vector_type(4))) float    f32x4;
typedef __attribute__((ext_vector_type(4))) unsigned short ushort4v;
typedef __attribute__((ext_vector_type(8))) unsigned short ushort8v;

// ---------- helpers ----------

__device__ __forceinline__ unsigned short f2bf(float f) {
    union { float f; unsigned u; } c; c.f = f;
    unsigned r = c.u + 0x7fffu + ((c.u >> 16) & 1u);   // RNE, inputs finite
    return (unsigned short)(r >> 16);
}

__device__ __forceinline__ float gelu_tanh(float x) {
    const float c0 = 0.7978845608028654f;  // sqrt(2/pi)
    const float c1 = 0.044715f;
    float u = c0 * (x + c1 * x * x * x);
    float t = 1.0f - 2.0f / (1.0f + __expf(2.0f * u));
    return 0.5f * x * (1.0f + t);
}

typedef const __attribute__((address_space(1))) void gbl_void_t;
typedef __attribute__((address_space(3))) void lds_void_t;

__device__ __forceinline__ void gload_lds16(const void* g, void* l) {
    __builtin_amdgcn_global_load_lds((gbl_void_t*)g, (lds_void_t*)l, 16, 0, 0);
}

// ---------- prep: transpose-convert w2 [E][F][H] f32 -> w2t [E][H][F] bf16 ----

__global__ void transpose_cvt(const float* __restrict__ in,
                              unsigned short* __restrict__ out) {
    __shared__ unsigned short tile[64][65];
    const int e  = blockIdx.z;
    const int f0 = blockIdx.x * 64;
    const int h0 = blockIdx.y * 64;
    const float*     src = in  + (size_t)e * FFN * HID;
    unsigned short*  dst = out + (size_t)e * HID * FFN;
    const int t  = threadIdx.x;
    const int tr = t >> 4;        // 0..15
    const int tc = (t & 15) * 4;  // 0..60
#pragma unroll
    for (int i = 0; i < 4; i++) {
        int f = i * 16 + tr;
        f32x4 v = *(const f32x4*)(src + (size_t)(f0 + f) * HID + h0 + tc);
#pragma unroll
        for (int j = 0; j < 4; j++) tile[f][tc + j] = f2bf(v[j]);
    }
    __syncthreads();
#pragma unroll
    for (int i = 0; i < 4; i++) {
        int h = i * 16 + tr;
        ushort4v o;
#pragma unroll
        for (int j = 0; j < 4; j++) o[j] = tile[tc + j][h];
        *(ushort4v*)(dst + (size_t)(h0 + h) * FFN + f0 + tc) = o;
    }
}

// ---------- GEMM1 fused-cvt: C=gelu(x@w1^T), f32 inputs, 8-phase R11 skeleton
// Staging = reg-stage: f32 loads issued 2 phases ahead -> f2bf cvt ->
// ds_write_b128 (swizzled dest, per-lane — rule #21 does not constrain
// ds_write). Writes placed AFTER MIDBAR's "memory" asm (stores cannot hoist
// above it); every LDS region's readers retire at their own lgkm0 BEFORE the
// barrier the write follows (same invariant as the gload version). All VMW
// machinery removed (loads are compiler-visible -> auto vmcnt).
// Write slots (identical regions to R11): ph1:A1(T+1) ph2:A0(T+2) ph3:B0(T+2)
// ph4:B1(T+2) ph5:A1(T+2) ph6:A0(T+3) ph7:B0(T+3) ph8:B1(T+3).
// Load slots 2 phases ahead, alternating parity regs gO/gE.

template <int GX, int GY>
__global__ __launch_bounds__(512, 2)
void gemm8f(const float* __restrict__ Af,
            const float* __restrict__ Bf,
            unsigned short* __restrict__ Cout, int M, int N, int K) {
    constexpr int BM = 256, BN = 256, BK = 64;
    constexpr int NH = 2, NI = 4, S = 32;
    constexpr int ABYTES = BM * BK * 2;   // 32768
    constexpr int BBYTES = BN * BK * 2;   // 32768
    constexpr int BUF = ABYTES + BBYTES;
    constexpr int NWG = NE * GX * GY;

    __shared__ __align__(16) char lds[2 * BUF];

    const int lin = blockIdx.x;
    const int wid = (lin & 7) * (NWG >> 3) + (lin >> 3);
    const int e   = wid / (GX * GY);
    const int rem = wid % (GX * GY);
    const int m0  = (rem % GX) * BM;
    const int n0  = (rem / GX) * BN;

    const float* Ae = Af + (size_t)e * M * K;
    const float* Be = Bf + (size_t)e * N * K;

    const int tid  = threadIdx.x;
    const int lane = tid & 63;
    const int w    = tid >> 6;
    const int wr   = w >> 2, wc = w & 3;
    const int fr   = lane & 15, fq = lane >> 4;

    // ---- staging addressing ----
    const int rA  = tid >> 3;             // 0..63
    const int kb  = (tid & 7) * 16;       // bf16-byte offset in 128B row
    const int kbs = kb ^ ((rA & 7) << 4); // swizzled bf16-byte offset
    const int eoff = kbs >> 1;            // f32 element offset (0..63, mult of 8)
    const float* aFb = Ae + (size_t)(m0 + rA) * K + eoff;
    const int   fB   = (rA / S) * 2 * S + (rA % S);
    const float* bFb = Be + (size_t)(n0 + fB) * K + eoff;
    char* dA0 = lds + rA * 128 + kb;
    char* dA1 = dA0 + BUF;
    char* dB0 = lds + ABYTES + fB * 128 + kb;
    char* dB1 = dB0 + BUF;

    auto LD_A = [&](int au, int kt, f32x4 (&g)[4]) {
        const float* s = aFb + (size_t)kt * 64;
        g[0] = *(const f32x4*)(s + (size_t)(au * 64) * K);
        g[1] = *(const f32x4*)(s + (size_t)(au * 64) * K + 4);
        g[2] = *(const f32x4*)(s + (size_t)(au * 64 + 128) * K);
        g[3] = *(const f32x4*)(s + (size_t)(au * 64 + 128) * K + 4);
    };
    auto LD_B = [&](int bu, int kt, f32x4 (&g)[4]) {
        const float* s = bFb + (size_t)kt * 64;
        g[0] = *(const f32x4*)(s + (size_t)(bu * S) * K);
        g[1] = *(const f32x4*)(s + (size_t)(bu * S) * K + 4);
        g[2] = *(const f32x4*)(s + (size_t)(bu * S + 128) * K);
        g[3] = *(const f32x4*)(s + (size_t)(bu * S + 128) * K + 4);
    };
    auto PACK = [&](const f32x4& lo, const f32x4& hi) {
        ushort8v o;
#pragma unroll
        for (int j = 0; j < 4; j++) { o[j] = f2bf(lo[j]); o[4 + j] = f2bf(hi[j]); }
        return o;
    };
    auto WR_A = [&](int au, char* d, f32x4 (&g)[4]) {
        *(ushort8v*)(d + (au * 64) * 128)       = PACK(g[0], g[1]);
        *(ushort8v*)(d + (au * 64 + 128) * 128) = PACK(g[2], g[3]);
    };
    auto WR_B = [&](int bu, char* d, f32x4 (&g)[4]) {
        *(ushort8v*)(d + (bu * S) * 128)        = PACK(g[0], g[1]);
        *(ushort8v*)(d + (bu * S + 128) * 128)  = PACK(g[2], g[3]);
    };

    // ---- LDS read bases (swizzled, identical to R11) ----
    const int kx0 = (fq * 16) ^ ((lane & 7) << 4);
    const char* paA = lds + (wr * 128 + fr) * 128;
    const char* paB = lds + ABYTES + (wc * (BN / 4) + fr) * 128;
    const char* pa0k0 = paA + kx0;        const char* pa0k1 = paA + (kx0 ^ 64);
    const char* pa1k0 = pa0k0 + BUF;      const char* pa1k1 = pa0k1 + BUF;
    const char* pb0k0 = paB + kx0;        const char* pb0k1 = paB + (kx0 ^ 64);
    const char* pb1k0 = pb0k0 + BUF;      const char* pb1k1 = pb0k1 + BUF;

    bf16x8 a[4][2], b0[NH][2], b1[NH][2];

    auto LDA = [&](const char* p0, const char* p1, int mq) {
#pragma unroll
        for (int mi = 0; mi < 4; mi++) {
            a[mi][0] = *(const bf16x8*)(p0 + mq * 8192 + mi * 2048);
            a[mi][1] = *(const bf16x8*)(p1 + mq * 8192 + mi * 2048);
        }
    };
    auto LDB = [&](const char* p0, const char* p1, int nq, bf16x8 (&bb)[NH][2]) {
#pragma unroll
        for (int ni = 0; ni < NH; ni++) {
            bb[ni][0] = *(const bf16x8*)(p0 + (nq * (BN / 8) + ni * 16) * 128);
            bb[ni][1] = *(const bf16x8*)(p1 + (nq * (BN / 8) + ni * 16) * 128);
        }
    };

    f32x4 acc[8][NI];

    auto MMQ = [&](int mq, int nq, bf16x8 (&bb)[NH][2]) {
        __builtin_amdgcn_s_setprio(1);
#pragma unroll
        for (int mi = 0; mi < 4; mi++)
#pragma unroll
            for (int ni = 0; ni < NH; ni++) {
                f32x4& c = acc[mq * 4 + mi][nq * NH + ni];
                c = __builtin_amdgcn_mfma_f32_16x16x32_bf16(a[mi][0], bb[ni][0], c, 0, 0, 0);
                c = __builtin_amdgcn_mfma_f32_16x16x32_bf16(a[mi][1], bb[ni][1], c, 0, 0, 0);
            }
        __builtin_amdgcn_s_setprio(0);
    };

#define MIDBAR()  __builtin_amdgcn_s_barrier();                                      \
                  asm volatile("s_waitcnt lgkmcnt(0)" ::: "memory")
#define ENDBAR()  __builtin_amdgcn_s_barrier()
#define LGHINT()  asm volatile("s_waitcnt lgkmcnt(8)" ::: "memory")

    const int NT   = K / BK;
    const int NTm1 = NT - 1;

    // prologue: straight-line stage T0 {A0,A1,B0,B1}, T1 {A0,B0,B1};
    // preload pipeline regs: gO = A1(T1) for ph1, gE = A0(T2) for ph2.
    f32x4 gO[4], gE[4];
    {
        f32x4 t0[4];
        LD_A(0, 0, t0); WR_A(0, dA0, t0);
        LD_A(1, 0, t0); WR_A(1, dA0, t0);
        LD_B(0, 0, t0); WR_B(0, dB0, t0);
        LD_B(1, 0, t0); WR_B(1, dB0, t0);
        LD_A(0, 1, t0); WR_A(0, dA1, t0);
        LD_B(0, 1, t0); WR_B(0, dB1, t0);
        LD_B(1, 1, t0); WR_B(1, dB1, t0);
    }
    LD_A(1, 1, gO);
    LD_A(0, (2 < NT ? 2 : NTm1), gE);
#pragma unroll
    for (int i = 0; i < 8; i++)
#pragma unroll
        for (int j = 0; j < NI; j++) acc[i][j] = f32x4{0.f, 0.f, 0.f, 0.f};
    asm volatile("s_waitcnt lgkmcnt(0)" ::: "memory");
    __builtin_amdgcn_s_barrier();

    const int NW = NT / 2;
    for (int ww = 0; ww < NW; ++ww) {
        const int T = 2 * ww;
        const int kt2 = (T + 2 < NT) ? T + 2 : NTm1;
        const int kt3 = (T + 3 < NT) ? T + 3 : NTm1;
        const int kt4 = (T + 4 < NT) ? T + 4 : NTm1;

        // ---- buf0 half: tile T ----
        LDA(pa0k0, pa0k1, 0); LDB(pb0k0, pb0k1, 0, b0); LGHINT();
        MIDBAR();
        WR_A(1, dA1, gO); LD_B(0, kt2, gO);          // ph1: write A1(T+1)
        MMQ(0, 0, b0); ENDBAR();
        LDB(pb0k0, pb0k1, 1, b1);
        MIDBAR();
        WR_A(0, dA0, gE); LD_B(1, kt2, gE);          // ph2: write A0(T+2)
        MMQ(0, 1, b1); ENDBAR();
        LDA(pa0k0, pa0k1, 1);
        MIDBAR();
        WR_B(0, dB0, gO); LD_A(1, kt2, gO);          // ph3: write B0(T+2)
        MMQ(1, 1, b1); ENDBAR();
        MIDBAR();
        WR_B(1, dB0, gE); LD_A(0, kt3, gE);          // ph4: write B1(T+2)
        MMQ(1, 0, b0); ENDBAR();
        // ---- buf1 half: tile T+1 ----
        LDA(pa1k0, pa1k1, 0); LDB(pb1k0, pb1k1, 0, b0); LGHINT();
        MIDBAR();
        WR_A(1, dA0, gO); LD_B(0, kt3, gO);          // ph5: write A1(T+2)
        MMQ(0, 0, b0); ENDBAR();
        LDB(pb1k0, pb1k1, 1, b1);
        MIDBAR();
        WR_A(0, dA1, gE); LD_B(1, kt3, gE);          // ph6: write A0(T+3)
        MMQ(0, 1, b1); ENDBAR();
        LDA(pa1k0, pa1k1, 1);
        MIDBAR();
        WR_B(0, dB1, gO); LD_A(1, kt3, gO);          // ph7: write B0(T+3)
        MMQ(1, 1, b1); ENDBAR();
        MIDBAR();
        WR_B(1, dB1, gE); LD_A(0, kt4, gE);          // ph8: write B1(T+3)
        MMQ(1, 0, b0); ENDBAR();
    }

    // epilogue: gelu -> bf16; C/D layout col = lane&15, row = (lane>>4)*4 + r
    const int r0 = m0 + wr * 128 + fq * 4;
    const int c0 = n0 + wc * (BN / 4) + fr;
    unsigned short* C = Cout + (size_t)e * M * N;
#pragma unroll
    for (int mi = 0; mi < 8; mi++)
#pragma unroll
        for (int ni = 0; ni < NI; ni++) {
            int row = r0 + mi * 16, col = c0 + ni * 16;
#pragma unroll
            for (int r = 0; r < 4; r++)
                C[(size_t)(row + r) * N + col] = f2bf(gelu_tanh(acc[mi][ni][r]));
        }
#undef MIDBAR
#undef ENDBAR
#undef LGHINT
}

// ---------- 8-phase GEMM-BT (R11, proven) for GEMM2 ------------------------

template <int BN, int GX, int GY, bool GELU>
__global__ __launch_bounds__(512, 2)
void gemm8p(const unsigned short* __restrict__ A,
            const unsigned short* __restrict__ B,
            void* __restrict__ Cout, int M, int N, int K) {
    constexpr int BM = 256, BK = 64;
    constexpr int NH = BN / 128;
    constexpr int NI = 2 * NH;
    constexpr int LB = BN / 128;
    constexpr int S  = BN / 8;
    constexpr int ABYTES = BM * BK * 2;
    constexpr int BBYTES = BN * BK * 2;
    constexpr int BUF = ABYTES + BBYTES;
    constexpr int VMC = 2 + 2 * LB;
    constexpr int NWG = NE * GX * GY;

    __shared__ __align__(16) char lds[2 * BUF];

    const int lin = blockIdx.x;
    const int wid = (lin & 7) * (NWG >> 3) + (lin >> 3);
    const int e   = wid / (GX * GY);
    const int rem = wid % (GX * GY);
    const int m0  = (rem % GX) * BM;
    const int n0  = (rem / GX) * BN;

    const size_t K2 = (size_t)K * 2;
    const char* Ae = (const char*)(A + (size_t)e * M * K);
    const char* Be = (const char*)(B + (size_t)e * N * K);

    const int tid  = threadIdx.x;
    const int lane = tid & 63;
    const int w    = tid >> 6;
    const int wr   = w >> 2, wc = w & 3;
    const int fr   = lane & 15, fq = lane >> 4;

    const int rA  = tid >> 3;
    const int kb  = (tid & 7) * 16;
    const int kbs = kb ^ ((rA & 7) << 4);
    const char* aptr = Ae + (size_t)(m0 + rA) * K2 + kbs;
    const int   fB   = (rA / S) * 2 * S + (rA % S);
    const char* bptr = Be + (size_t)(n0 + fB) * K2 + kbs;
    char* dA0 = lds + rA * 128 + kb;
    char* dA1 = dA0 + BUF;
    char* dB0 = lds + ABYTES + fB * 128 + kb;
    char* dB1 = dB0 + BUF;

    auto SA = [&](int au, int kt, char* d) {
        const char* s = aptr + (size_t)kt * 128;
#pragma unroll
        for (int i = 0; i < 2; i++)
            gload_lds16(s + (size_t)(au * 64 + i * 128) * K2,
                        d + (au * 64 + i * 128) * 128);
    };
    auto SB = [&](int bu, int kt, char* d) {
        const char* s = bptr + (size_t)kt * 128;
#pragma unroll
        for (int i = 0; i < LB; i++)
            gload_lds16(s + (size_t)(bu * S + i * 128) * K2,
                        d + (bu * S + i * 128) * 128);
    };

    const int kx0 = (fq * 16) ^ ((lane & 7) << 4);
    const char* paA = lds + (wr * 128 + fr) * 128;
    const char* paB = lds + ABYTES + (wc * (BN / 4) + fr) * 128;
    const char* pa0k0 = paA + kx0;        const char* pa0k1 = paA + (kx0 ^ 64);
    const char* pa1k0 = pa0k0 + BUF;      const char* pa1k1 = pa0k1 + BUF;
    const char* pb0k0 = paB + kx0;        const char* pb0k1 = paB + (kx0 ^ 64);
    const char* pb1k0 = pb0k0 + BUF;      const char* pb1k1 = pb0k1 + BUF;

    f32x4 acc[8][NI];
#pragma unroll
    for (int i = 0; i < 8; i++)
#pragma unroll
        for (int j = 0; j < NI; j++) acc[i][j] = f32x4{0.f, 0.f, 0.f, 0.f};

    bf16x8 a[4][2], b0[NH][2], b1[NH][2];

    auto LDA = [&](const char* p0, const char* p1, int mq) {
#pragma unroll
        for (int mi = 0; mi < 4; mi++) {
            a[mi][0] = *(const bf16x8*)(p0 + mq * 8192 + mi * 2048);
            a[mi][1] = *(const bf16x8*)(p1 + mq * 8192 + mi * 2048);
        }
    };
    auto LDB = [&](const char* p0, const char* p1, int nq, bf16x8 (&bb)[NH][2]) {
#pragma unroll
        for (int ni = 0; ni < NH; ni++) {
            bb[ni][0] = *(const bf16x8*)(p0 + (nq * (BN / 8) + ni * 16) * 128);
            bb[ni][1] = *(const bf16x8*)(p1 + (nq * (BN / 8) + ni * 16) * 128);
        }
    };
    auto MMQ = [&](int mq, int nq, bf16x8 (&bb)[NH][2]) {
        __builtin_amdgcn_s_setprio(1);
#pragma unroll
        for (int mi = 0; mi < 4; mi++)
#pragma unroll
            for (int ni = 0; ni < NH; ni++) {
                f32x4& c = acc[mq * 4 + mi][nq * NH + ni];
                c = __builtin_amdgcn_mfma_f32_16x16x32_bf16(a[mi][0], bb[ni][0], c, 0, 0, 0);
                c = __builtin_amdgcn_mfma_f32_16x16x32_bf16(a[mi][1], bb[ni][1], c, 0, 0, 0);
            }
        __builtin_amdgcn_s_setprio(0);
    };

#define MIDBAR()  __builtin_amdgcn_s_barrier();                                      \
                  asm volatile("s_waitcnt lgkmcnt(0)" ::: "memory")
#define ENDBAR()  __builtin_amdgcn_s_barrier()
#define LGHINT()  asm volatile("s_waitcnt lgkmcnt(8)" ::: "memory")
#define VMW()     asm volatile("s_waitcnt vmcnt(%0)" :: "n"(VMC) : "memory")

    const int NT   = K / BK;
    const int NTm1 = NT - 1;

    SA(0, 0, dA0); SB(0, 0, dB0); SB(1, 0, dB0); SA(1, 0, dA0);
    SA(0, 1, dA1); SB(0, 1, dB1); SB(1, 1, dB1);
    VMW();
    __builtin_amdgcn_s_barrier();

    const int NW = NT / 2;
    for (int ww = 0; ww < NW; ++ww) {
        const int T = 2 * ww;
        const int kt1 = T + 1;
        const int kt2 = (T + 2 < NT) ? T + 2 : NTm1;
        const int kt3 = (T + 3 < NT) ? T + 3 : NTm1;

        LDA(pa0k0, pa0k1, 0); LDB(pb0k0, pb0k1, 0, b0); SA(1, kt1, dA1); LGHINT();
        MIDBAR(); MMQ(0, 0, b0); ENDBAR();
        LDB(pb0k0, pb0k1, 1, b1); SA(0, kt2, dA0);
        MIDBAR(); MMQ(0, 1, b1); ENDBAR();
        LDA(pa0k0, pa0k1, 1); SB(0, kt2, dB0);
        MIDBAR(); MMQ(1, 1, b1); ENDBAR();
        SB(1, kt2, dB0);
        MIDBAR(); MMQ(1, 0, b0); VMW(); ENDBAR();
        LDA(pa1k0, pa1k1, 0); LDB(pb1k0, pb1k1, 0, b0); SA(1, kt2, dA0); LGHINT();
        MIDBAR(); MMQ(0, 0, b0); ENDBAR();
        LDB(pb1k0, pb1k1, 1, b1); SA(0, kt3, dA1);
        MIDBAR(); MMQ(0, 1, b1); ENDBAR();
        LDA(pa1k0, pa1k1, 1); SB(0, kt3, dB1);
        MIDBAR(); MMQ(1, 1, b1); ENDBAR();
        SB(1, kt3, dB1);
        MIDBAR(); MMQ(1, 0, b0); VMW(); ENDBAR();
    }
    asm volatile("s_waitcnt vmcnt(0)" ::: "memory");

    const int r0 = m0 + wr * 128 + fq * 4;
    const int c0 = n0 + wc * (BN / 4) + fr;
    if constexpr (GELU) {
        unsigned short* C = (unsigned short*)Cout + (size_t)e * M * N;
#pragma unroll
        for (int mi = 0; mi < 8; mi++)
#pragma unroll
            for (int ni = 0; ni < NI; ni++) {
                int row = r0 + mi * 16, col = c0 + ni * 16;
#pragma unroll
                for (int r = 0; r < 4; r++)
                    C[(size_t)(row + r) * N + col] = f2bf(gelu_tanh(acc[mi][ni][r]));
            }
    } else {
        float* C = (float*)Cout + (size_t)e * M * N;
#pragma unroll
        for (int mi = 0; mi < 8; mi++)
#pragma unroll
            for (int ni = 0; ni < NI; ni++) {
                int row = r0 + mi * 16, col = c0 + ni * 16;
#pragma unroll
                for (int r = 0; r < 4; r++)
                    C[(size_t)(row + r) * N + col] = acc[mi][ni][r];
            }
    }
#undef MIDBAR
#undef ENDBAR
#undef LGHINT
#undef VMW
}

// ---------- fallback: fused fp32, zero workspace (correctness insurance) ----------

__global__ void fused_fallback(const float* __restrict__ x,
                               const float* __restrict__ w1,
                               const float* __restrict__ w2,
                               float* __restrict__ out) {
    __shared__ float xs[HID];
    __shared__ float hs[FFN];
    const int tok = blockIdx.x;
    const int e   = tok / TPE;
    const float* w1e = w1 + (size_t)e * FFN * HID;
    const float* w2e = w2 + (size_t)e * FFN * HID;
    const int t = threadIdx.x;
    for (int i = t; i < HID; i += 256) xs[i] = x[(size_t)tok * HID + i];
    __syncthreads();
    for (int f = t; f < FFN; f += 256) {
        const float* wr_ = w1e + (size_t)f * HID;
        float s = 0.f;
        for (int k = 0; k < HID; k++) s += xs[k] * wr_[k];
        hs[f] = gelu_tanh(s);
    }
    __syncthreads();
    for (int h = t; h < HID; h += 256) {
        float s = 0.f;
        for (int f = 0; f < FFN; f++) s += hs[f] * w2e[(size_t)f * HID + h];
        out[(size_t)tok * HID + h] = s;
    }
}

// ---------- launch ----------

extern "C" void kernel_launch(void* const* d_in, const int* in_sizes, int n_in,
                              void* d_out, int out_size, void* d_ws, size_t ws_size,
                              hipStream_t stream) {
    const float* x  = (const float*)d_in[0];
    const float* w1 = (const float*)d_in[1];
    const float* w2 = (const float*)d_in[2];
    float* out = (float*)d_out;

    const size_t W2B = (size_t)NE * FFN * HID * 2;   // 64 MB  bf16 w2t
    const size_t HB  = (size_t)TOK * FFN * 2;        // 64 MB  bf16 h
    const size_t need = W2B + HB;                    // 128 MB

    if (ws_size >= need) {
        char* ws = (char*)d_ws;
        unsigned short* w2t = (unsigned short*)ws;
        unsigned short* hb  = (unsigned short*)(ws + W2B);

        // prep: only w2 transpose-convert (192 MB traffic)
        transpose_cvt<<<dim3(FFN / 64, HID / 64, NE), 256, 0, stream>>>(w2, w2t);

        // GEMM1 fused-cvt: h = gelu(x @ w1^T), f32 inputs -> 512 blocks
        gemm8f<TPE / 256, FFN / 256><<<NE * (TPE / 256) * (FFN / 256), 512, 0, stream>>>(
            x, w1, hb, TPE, FFN, HID);
        // GEMM2: out = h @ w2t^T -> 256 blocks (R11 proven 8-phase)
        gemm8p<128, TPE / 256, HID / 128, false><<<NE * (TPE / 256) * (HID / 128), 512, 0, stream>>>(
            hb, w2t, out, TPE, HID, FFN);
    } else {
        fused_fallback<<<TOK, 256, 0, stream>>>(x, w1, w2, out);
    }
}